// Round 12
// baseline (94.872 us; speedup 1.0000x reference)
//
#include <hip/hip_runtime.h>
#include <math.h>

#define TB   256
#define HH   128     // input H=W
#define OHW  64      // output H=W
#define TR   8       // output rows per tile (8 tiles/plane)
#define XR   21      // slab rows: 2*TR+5
#define N0C  68      // n0 row stride; out col c at index c+2

typedef float f32x2 __attribute__((ext_vector_type(2)));

__device__ __forceinline__ float sigmoidf(float z) {
    return 1.0f / (1.0f + __expf(-z));
}

__device__ __forceinline__ void gl2lds16(const float* g, float* l) {
    __builtin_amdgcn_global_load_lds(
        (const __attribute__((address_space(1))) void*)g,
        (__attribute__((address_space(3))) void*)l, 16, 0, 0);
}
__device__ __forceinline__ void gl2lds4(const float* g, float* l) {
    __builtin_amdgcn_global_load_lds(
        (const __attribute__((address_space(1))) void*)g,
        (__attribute__((address_space(3))) void*)l, 4, 0, 0);
}

// One block = one 8-row tile. 13.2 KB LDS; wave-slot limit gives 8 blocks/CU
// (32 waves) so resident blocks sit in different stage/compute phases and the
// CU scheduler interleaves them. Staging is fire-and-forget global_load_lds.
__global__ __launch_bounds__(TB, 8) void fused_densenet_kernel(
    const float* __restrict__ x,
    const float* __restrict__ maxgate,
    const float* __restrict__ mb,
    const float* __restrict__ pconvs,
    const float* __restrict__ pbs,
    const float* __restrict__ pgates,
    const float* __restrict__ gbs,
    float* __restrict__ out)
{
    __shared__ float xs[XR][HH];          // contiguous slab (10.5 KB)
    __shared__ float n0s[TR + 2][N0C];    // n0 with 1-halo (2.7 KB)

    const int t     = threadIdx.x;
    const int lane  = t & 63;
    const int wv    = t >> 6;             // wave 0..3
    const int bid   = blockIdx.x;
    const int tile  = bid & 7;
    const int plane = bid >> 3;           // b*256 + c
    const int c     = plane & 255;
    const int r0    = tile * TR;

    // ---- weights/biases (block-uniform address -> scalar-resident) ----
    // ws rows: 0=maxgate 1=p0 2=p1 3=p2 4=p3 5=gate0 6=gate2(leaf1+node)
    float ws[7][9];
#pragma unroll
    for (int i = 0; i < 9; ++i) {
        ws[0][i] = maxgate[c * 9  + i];
        ws[1][i] = pconvs [c * 36 + i * 4 + 0];
        ws[2][i] = pconvs [c * 36 + i * 4 + 1];
        ws[3][i] = pconvs [c * 36 + i * 4 + 2];
        ws[4][i] = pconvs [c * 36 + i * 4 + 3];
        ws[5][i] = pgates [c * 27 + i * 3 + 0];
        ws[6][i] = pgates [c * 27 + i * 3 + 2];
    }
    const float bmax = mb[c];
    const float bp0 = pbs[c * 4 + 0], bp1 = pbs[c * 4 + 1];
    const float bp2 = pbs[c * 4 + 2], bp3 = pbs[c * 4 + 3];
    const float bg0 = gbs[c * 3 + 0];   // leaf0 gate bias
    const float bg1 = gbs[c * 3 + 1];   // leaf1 gate bias
    const float bg2 = gbs[c * 3 + 2];   // node gate bias

    const float* xplane = x + (size_t)plane * (HH * HH);

    // ---- async stage: input rows 2r0-3 .. 2r0+17 into xs, zero-pad at edges ----
    {
        const int ir0  = 2 * r0 - 3;
        const int lo   = ir0 < 0 ? 0 : ir0;
        const int hie  = ir0 + XR - 1;
        const int hi   = hie > HH - 1 ? HH - 1 : hie;
        const int ztop = lo - ir0;                 // 3 for tile 0, else 0
        const int zbot = hie - hi;                 // 2 for tile 7, else 0
        for (int i = t; i < ztop * HH; i += TB) (&xs[0][0])[i] = 0.f;
        for (int i = t; i < zbot * HH; i += TB) (&xs[XR - zbot][0])[i] = 0.f;
        const int    nfl  = (hi - lo + 1) * HH;    // multiple of 128
        const float* gsrc = xplane + lo * HH;
        float*       ldst = &xs[ztop][0];
        const int nchunk = nfl >> 8;               // 1KB chunks (64 lanes x 16B)
        for (int k = wv; k < nchunk; k += TB / 64)
            gl2lds16(gsrc + (k << 8) + lane * 4, ldst + (k << 8));
        if ((nfl & 255) && wv == 0) {              // 512B tail
            const int off = nchunk << 8;
            gl2lds4(gsrc + off + lane,      ldst + off);
            gl2lds4(gsrc + off + 64 + lane, ldst + off + 64);
        }
        // n0 side cols (gc = -1 and 64) are outside the image -> always 0
        if (t < 2 * (TR + 2)) n0s[t >> 1][(t & 1) ? 66 : 1] = 0.f;
    }
    __syncthreads();                               // slab + side zeros ready

    // ---- n0 halo rows (gr = r0-1, r0+TR; zero outside image) ----
    if (t < 132) {
        const int hb  = (t >= 66);                 // 0 top, 1 bottom
        const int cc2 = hb ? t - 66 : t;           // 0..65
        const int gc  = cc2 - 1;                   // out col -1..64
        const int gr  = hb ? r0 + TR : r0 - 1;
        float n0v = 0.f;
        if ((unsigned)gr < (unsigned)OHW && (unsigned)gc < (unsigned)OHW) {
            const int sb = hb ? 2 * TR + 2 : 0;    // slab row base
            float ag = 0.f, a0 = 0.f, a1 = 0.f;
#pragma unroll
            for (int dr = 0; dr < 3; ++dr) {
                const float* row = &xs[sb + dr][0];
                const float w0 = (gc > 0) ? row[2 * gc - 1] : 0.f;
                const float w1 = row[2 * gc];
                const float w2 = row[2 * gc + 1];
                ag += w0 * ws[5][3*dr] + w1 * ws[5][3*dr+1] + w2 * ws[5][3*dr+2];
                a0 += w0 * ws[1][3*dr] + w1 * ws[1][3*dr+1] + w2 * ws[1][3*dr+2];
                a1 += w0 * ws[2][3*dr] + w1 * ws[2][3*dr+1] + w2 * ws[2][3*dr+2];
            }
            const float sg = sigmoidf(ag + bg0);
            n0v = sg * (a0 + bp0) + (1.f - sg) * (a1 + bp1);
        }
        n0s[hb ? TR + 1 : 0][cc2 + 1] = n0v;
    }

    // ---- stage 1 interior: exactly 1 row x 2 cols per thread ----
    const int p  = t & 31;             // col pair: out cols {2p, 2p+1}
    const int lr = t >> 5;             // local output row 0..7
    const int gr = r0 + lr;
    float o1a, o1b, n1a, n1b;
    {
        float a[7][2];
#pragma unroll
        for (int ci = 0; ci < 7; ++ci) { a[ci][0] = 0.f; a[ci][1] = 0.f; }
        float mp0 = -INFINITY, mp1 = -INFINITY;
#pragma unroll
        for (int dr = 0; dr < 3; ++dr) {
            const float* row = &xs[2 * lr + 2 + dr][0];
            const float  v0 = (p > 0) ? row[4 * p - 1] : 0.f;
            const float4 vv = *reinterpret_cast<const float4*>(&row[4 * p]);
            const bool rowok = (gr > 0) | (dr > 0);
            const float h0 = fmaxf(fmaxf((p > 0) ? v0 : -INFINITY, vv.x), vv.y);
            const float h1 = fmaxf(fmaxf(vv.y, vv.z), vv.w);
            mp0 = fmaxf(mp0, rowok ? h0 : -INFINITY);
            mp1 = fmaxf(mp1, rowok ? h1 : -INFINITY);
#pragma unroll
            for (int ci = 0; ci < 7; ++ci) {
                a[ci][0] += v0   * ws[ci][3*dr] + vv.x * ws[ci][3*dr+1] + vv.y * ws[ci][3*dr+2];
                a[ci][1] += vv.y * ws[ci][3*dr] + vv.z * ws[ci][3*dr+1] + vv.w * ws[ci][3*dr+2];
            }
        }
        const float sg0a = sigmoidf(a[5][0] + bg0);
        const float sg0b = sigmoidf(a[5][1] + bg0);
        const float n0a = sg0a * (a[1][0] + bp0) + (1.f - sg0a) * (a[2][0] + bp1);
        const float n0b = sg0b * (a[1][1] + bp0) + (1.f - sg0b) * (a[2][1] + bp1);
        *reinterpret_cast<f32x2*>(&n0s[lr + 1][2 * p + 2]) = (f32x2){ n0a, n0b };
        const float sg1a = sigmoidf(a[6][0] + bg1);    // leaf1 gate: bias gbs[:,1]
        const float sg1b = sigmoidf(a[6][1] + bg1);
        n1a = sg1a * (a[3][0] + bp2) + (1.f - sg1a) * (a[4][0] + bp3);
        n1b = sg1b * (a[3][1] + bp2) + (1.f - sg1b) * (a[4][1] + bp3);
        o1a = mp0 * (a[0][0] + bmax);
        o1b = mp1 * (a[0][1] + bmax);
    }
    __syncthreads();

    // ---- stage 2: node gate conv on n0 (stride 1, pad 1) + combine + store ----
    {
        float ag0 = 0.f, ag1 = 0.f, n0c0 = 0.f, n0c1 = 0.f;
#pragma unroll
        for (int dr = 0; dr < 3; ++dr) {
            const float e0  = n0s[lr + dr][2 * p + 1];
            const f32x2 mid = *reinterpret_cast<const f32x2*>(&n0s[lr + dr][2 * p + 2]);
            const float e3  = n0s[lr + dr][2 * p + 4];
            ag0 += e0    * ws[6][3*dr] + mid.x * ws[6][3*dr+1] + mid.y * ws[6][3*dr+2];
            ag1 += mid.x * ws[6][3*dr] + mid.y * ws[6][3*dr+1] + e3    * ws[6][3*dr+2];
            if (dr == 1) { n0c0 = mid.x; n0c1 = mid.y; }
        }
        const float ga = sigmoidf(ag0 + bg2);          // node gate: bias gbs[:,2]
        const float gb = sigmoidf(ag1 + bg2);
        f32x2 rv;
        rv.x = o1a + n0c0 * ga + n1a * (1.f - ga);
        rv.y = o1b + n0c1 * gb + n1b * (1.f - gb);
        __builtin_nontemporal_store(rv,
            reinterpret_cast<f32x2*>(out + (size_t)plane * (OHW * OHW)
                                     + gr * OHW + 2 * p));
    }
}

extern "C" void kernel_launch(void* const* d_in, const int* in_sizes, int n_in,
                              void* d_out, int out_size, void* d_ws, size_t ws_size,
                              hipStream_t stream) {
    const float* x       = (const float*)d_in[0];
    const float* maxgate = (const float*)d_in[1];
    const float* mb      = (const float*)d_in[2];
    const float* pconvs  = (const float*)d_in[3];
    const float* pbs     = (const float*)d_in[4];
    const float* pgates  = (const float*)d_in[5];
    const float* gbs     = (const float*)d_in[6];
    float* out           = (float*)d_out;

    const int blocks = 16 * 256 * 8;   // one 8-row tile per block
    fused_densenet_kernel<<<blocks, TB, 0, stream>>>(
        x, maxgate, mb, pconvs, pbs, pgates, gbs, out);
}

// Round 13
// 80.175 us; speedup vs baseline: 1.1833x; 1.1833x over previous
//
#include <hip/hip_runtime.h>
#include <math.h>

#define TB   256
#define HH   128     // input H=W
#define OHW  64      // output H=W
#define TR   16      // output rows per tile (4 tiles/plane)
#define XR   37      // slab rows: 2*TR+5
#define N0C  68      // n0 row stride; out col c at index c+2
#define NBLK (16 * 256 * 4)
#define CPX  (NBLK / 8)     // blocks per XCD chunk

typedef float f32x2 __attribute__((ext_vector_type(2)));

__device__ __forceinline__ float sigmoidf(float z) {
    return 1.0f / (1.0f + __expf(-z));
}

__device__ __forceinline__ void gl2lds16(const float* g, float* l) {
    __builtin_amdgcn_global_load_lds(
        (const __attribute__((address_space(1))) void*)g,
        (__attribute__((address_space(3))) void*)l, 16, 0, 0);
}
__device__ __forceinline__ void gl2lds4(const float* g, float* l) {
    __builtin_amdgcn_global_load_lds(
        (const __attribute__((address_space(1))) void*)g,
        (__attribute__((address_space(3))) void*)l, 4, 0, 0);
}

// R11 champion + XCD-aware blockIdx swizzle: HW round-robins blockIdx.x
// across the 8 XCDs, so remapping l = (bid&7)*CPX + bid>>3 gives each XCD a
// contiguous 512-plane range -> tile halo re-reads hit the XCD-local L2.
__global__ __launch_bounds__(TB, 6) void fused_densenet_kernel(
    const float* __restrict__ x,
    const float* __restrict__ maxgate,
    const float* __restrict__ mb,
    const float* __restrict__ pconvs,
    const float* __restrict__ pbs,
    const float* __restrict__ pgates,
    const float* __restrict__ gbs,
    float* __restrict__ out)
{
    __shared__ float xs[XR][HH];          // contiguous slab (18.5 KB)
    __shared__ float n0s[TR + 2][N0C];    // n0 with 1-halo (4.9 KB)

    const int t     = threadIdx.x;
    const int lane  = t & 63;
    const int wv    = t >> 6;             // wave 0..3
    const int bid   = blockIdx.x;
    const int l     = (bid & 7) * CPX + (bid >> 3);   // bijective XCD swizzle
    const int tile  = l & 3;
    const int plane = l >> 2;             // b*256 + c
    const int c     = plane & 255;
    const int r0    = tile * TR;

    // ---- weights/biases (block-uniform address -> scalar-resident) ----
    // ws rows: 0=maxgate 1=p0 2=p1 3=p2 4=p3 5=gate0 6=gate2(leaf1+node)
    float ws[7][9];
#pragma unroll
    for (int i = 0; i < 9; ++i) {
        ws[0][i] = maxgate[c * 9  + i];
        ws[1][i] = pconvs [c * 36 + i * 4 + 0];
        ws[2][i] = pconvs [c * 36 + i * 4 + 1];
        ws[3][i] = pconvs [c * 36 + i * 4 + 2];
        ws[4][i] = pconvs [c * 36 + i * 4 + 3];
        ws[5][i] = pgates [c * 27 + i * 3 + 0];
        ws[6][i] = pgates [c * 27 + i * 3 + 2];
    }
    const float bmax = mb[c];
    const float bp0 = pbs[c * 4 + 0], bp1 = pbs[c * 4 + 1];
    const float bp2 = pbs[c * 4 + 2], bp3 = pbs[c * 4 + 3];
    const float bg0 = gbs[c * 3 + 0];   // leaf0 gate bias
    const float bg1 = gbs[c * 3 + 1];   // leaf1 gate bias
    const float bg2 = gbs[c * 3 + 2];   // node gate bias

    const float* xplane = x + (size_t)plane * (HH * HH);

    // ---- async stage: input rows 2r0-3 .. 2r0+33 into xs, zero-pad at edges ----
    {
        const int ir0  = 2 * r0 - 3;
        const int lo   = ir0 < 0 ? 0 : ir0;
        const int hie  = ir0 + XR - 1;
        const int hi   = hie > HH - 1 ? HH - 1 : hie;
        const int ztop = lo - ir0;                 // 3 for tile 0, else 0
        const int zbot = hie - hi;                 // 2 for tile 3, else 0
        for (int i = t; i < ztop * HH; i += TB) (&xs[0][0])[i] = 0.f;
        for (int i = t; i < zbot * HH; i += TB) (&xs[XR - zbot][0])[i] = 0.f;
        const int    nfl  = (hi - lo + 1) * HH;    // multiple of 128
        const float* gsrc = xplane + lo * HH;
        float*       ldst = &xs[ztop][0];
        const int nchunk = nfl >> 8;               // 1KB chunks (64 lanes x 16B)
        for (int k = wv; k < nchunk; k += TB / 64)
            gl2lds16(gsrc + (k << 8) + lane * 4, ldst + (k << 8));
        if ((nfl & 255) && wv == 0) {              // 512B tail
            const int off = nchunk << 8;
            gl2lds4(gsrc + off + lane,      ldst + off);
            gl2lds4(gsrc + off + 64 + lane, ldst + off + 64);
        }
        // n0 side cols (gc = -1 and 64) are outside the image -> always 0
        if (t < 2 * (TR + 2)) n0s[t >> 1][(t & 1) ? 66 : 1] = 0.f;
    }
    __syncthreads();                               // slab + side zeros ready

    // ---- n0 halo rows (gr = r0-1, r0+TR; zero outside image) ----
    if (t < 132) {
        const int hb  = (t >= 66);                 // 0 top, 1 bottom
        const int cc2 = hb ? t - 66 : t;           // 0..65
        const int gc  = cc2 - 1;                   // out col -1..64
        const int gr  = hb ? r0 + TR : r0 - 1;
        float n0v = 0.f;
        if ((unsigned)gr < (unsigned)OHW && (unsigned)gc < (unsigned)OHW) {
            const int sb = hb ? 2 * TR + 2 : 0;    // slab row base
            float ag = 0.f, a0 = 0.f, a1 = 0.f;
#pragma unroll
            for (int dr = 0; dr < 3; ++dr) {
                const float* row = &xs[sb + dr][0];
                const float w0 = (gc > 0) ? row[2 * gc - 1] : 0.f;
                const float w1 = row[2 * gc];
                const float w2 = row[2 * gc + 1];
                ag += w0 * ws[5][3*dr] + w1 * ws[5][3*dr+1] + w2 * ws[5][3*dr+2];
                a0 += w0 * ws[1][3*dr] + w1 * ws[1][3*dr+1] + w2 * ws[1][3*dr+2];
                a1 += w0 * ws[2][3*dr] + w1 * ws[2][3*dr+1] + w2 * ws[2][3*dr+2];
            }
            const float sg = sigmoidf(ag + bg0);
            n0v = sg * (a0 + bp0) + (1.f - sg) * (a1 + bp1);
        }
        n0s[hb ? TR + 1 : 0][cc2 + 1] = n0v;
    }

    // ---- stage 1 interior: 2 cols x 1 row per micro-step, rows g0 & g0+8 ----
    const int p  = t & 31;             // col pair: out cols {2p, 2p+1}
    const int g0 = t >> 5;             // 0..7
    float out1[2][2], n1v[2][2];

#pragma unroll
    for (int k = 0; k < 2; ++k) {
        const int lr = g0 + 8 * k;
        const int gr = r0 + lr;
        float a[7][2];
#pragma unroll
        for (int ci = 0; ci < 7; ++ci) { a[ci][0] = 0.f; a[ci][1] = 0.f; }
        float mp0 = -INFINITY, mp1 = -INFINITY;
#pragma unroll
        for (int dr = 0; dr < 3; ++dr) {
            const float* row = &xs[2 * lr + 2 + dr][0];
            const float  v0 = (p > 0) ? row[4 * p - 1] : 0.f;
            const float4 vv = *reinterpret_cast<const float4*>(&row[4 * p]);
            const bool rowok = (gr > 0) | (dr > 0);
            const float h0 = fmaxf(fmaxf((p > 0) ? v0 : -INFINITY, vv.x), vv.y);
            const float h1 = fmaxf(fmaxf(vv.y, vv.z), vv.w);
            mp0 = fmaxf(mp0, rowok ? h0 : -INFINITY);
            mp1 = fmaxf(mp1, rowok ? h1 : -INFINITY);
#pragma unroll
            for (int ci = 0; ci < 7; ++ci) {
                a[ci][0] += v0   * ws[ci][3*dr] + vv.x * ws[ci][3*dr+1] + vv.y * ws[ci][3*dr+2];
                a[ci][1] += vv.y * ws[ci][3*dr] + vv.z * ws[ci][3*dr+1] + vv.w * ws[ci][3*dr+2];
            }
        }
        const float sg0a = sigmoidf(a[5][0] + bg0);
        const float sg0b = sigmoidf(a[5][1] + bg0);
        const float n0a = sg0a * (a[1][0] + bp0) + (1.f - sg0a) * (a[2][0] + bp1);
        const float n0b = sg0b * (a[1][1] + bp0) + (1.f - sg0b) * (a[2][1] + bp1);
        *reinterpret_cast<f32x2*>(&n0s[lr + 1][2 * p + 2]) = (f32x2){ n0a, n0b };
        const float sg1a = sigmoidf(a[6][0] + bg1);    // leaf1 gate: bias gbs[:,1]
        const float sg1b = sigmoidf(a[6][1] + bg1);
        n1v[k][0] = sg1a * (a[3][0] + bp2) + (1.f - sg1a) * (a[4][0] + bp3);
        n1v[k][1] = sg1b * (a[3][1] + bp2) + (1.f - sg1b) * (a[4][1] + bp3);
        out1[k][0] = mp0 * (a[0][0] + bmax);
        out1[k][1] = mp1 * (a[0][1] + bmax);
    }
    __syncthreads();

    // ---- stage 2: node gate conv on n0 (stride 1, pad 1) + combine + store ----
    float* oplane = out + (size_t)plane * (OHW * OHW);
#pragma unroll
    for (int k = 0; k < 2; ++k) {
        const int lr = g0 + 8 * k;
        float ag0 = 0.f, ag1 = 0.f, n0c0 = 0.f, n0c1 = 0.f;
#pragma unroll
        for (int dr = 0; dr < 3; ++dr) {
            const float e0  = n0s[lr + dr][2 * p + 1];
            const f32x2 mid = *reinterpret_cast<const f32x2*>(&n0s[lr + dr][2 * p + 2]);
            const float e3  = n0s[lr + dr][2 * p + 4];
            ag0 += e0    * ws[6][3*dr] + mid.x * ws[6][3*dr+1] + mid.y * ws[6][3*dr+2];
            ag1 += mid.x * ws[6][3*dr] + mid.y * ws[6][3*dr+1] + e3    * ws[6][3*dr+2];
            if (dr == 1) { n0c0 = mid.x; n0c1 = mid.y; }
        }
        const float ga = sigmoidf(ag0 + bg2);          // node gate: bias gbs[:,2]
        const float gb = sigmoidf(ag1 + bg2);
        f32x2 rv;
        rv.x = out1[k][0] + n0c0 * ga + n1v[k][0] * (1.f - ga);
        rv.y = out1[k][1] + n0c1 * gb + n1v[k][1] * (1.f - gb);
        __builtin_nontemporal_store(rv,
            reinterpret_cast<f32x2*>(oplane + (r0 + lr) * OHW + 2 * p));
    }
}

extern "C" void kernel_launch(void* const* d_in, const int* in_sizes, int n_in,
                              void* d_out, int out_size, void* d_ws, size_t ws_size,
                              hipStream_t stream) {
    const float* x       = (const float*)d_in[0];
    const float* maxgate = (const float*)d_in[1];
    const float* mb      = (const float*)d_in[2];
    const float* pconvs  = (const float*)d_in[3];
    const float* pbs     = (const float*)d_in[4];
    const float* pgates  = (const float*)d_in[5];
    const float* gbs     = (const float*)d_in[6];
    float* out           = (float*)d_out;

    fused_densenet_kernel<<<NBLK, TB, 0, stream>>>(
        x, maxgate, mb, pconvs, pbs, pgates, gbs, out);
}